// Round 1
// 519.766 us; speedup vs baseline: 1.2890x; 1.2890x over previous
//
#include <hip/hip_runtime.h>

typedef unsigned short u16;
typedef unsigned int u32;

#define N_ATOM   50000
#define M_NBR    12
#define A_FEA    128
#define NBR_FEA  64
#define KDIM     320
#define CDIM     256
#define ROWS     600000
#define RPB      48          // rows per block (= 4 atoms)
#define NBLK     12500       // 600000 / 48
#define KC       10          // K chunks of 32
#define EPSV     1e-5f
#define A_PITCH  656         // (320+8) bf16 * 2B, padded row pitch in bytes

using frag  = __attribute__((ext_vector_type(8))) short;
using f32x4 = __attribute__((ext_vector_type(4))) float;

// ---- workspace layout (float offsets) ----
#define WS_SUM1      0        // 256 (red1 adds here)
#define WS_SUMSQ1    256      // 256 (contiguous with SUM1)
#define WS_CNT       512
#define WS_SUM2      516      // 128
#define WS_SUMSQ2    644      // 128 (contiguous with SUM2)
#define WS_STATS_END 772
#define WS_SCALE1    1024
#define WS_SHIFT1    1280
#define WS_SCALE2    1536
#define WS_SHIFT2    1664
#define WS_NBR       2048                      // 50000*128 floats
#define WS_W_FOFF    (2048 + 6400000)          // swizzled W: 81920 u16 = 40960 floats
#define WS_P_FOFF    (2048 + 6400000 + 40960)  // per-block partials: p1 12500*512 / p2 12500*256
#define WS_G_FOFF    (WS_P_FOFF + 6400000)     // H: u32[600000][128] f/k bf16 pairs = 307.2 MB
#define WS_NEED_BYTES 358572032ull

__device__ __forceinline__ u32 fbits(float f) { union { float f; u32 u; } v; v.f = f; return v.u; }
__device__ __forceinline__ float bits2f(u32 u) { union { u32 u; float f; } v; v.u = u; return v.f; }
// round-half-up bf16 pair pack: low16 = bf(a), high16 = bf(b)  (1 perm + 2 add)
__device__ __forceinline__ u32 pkbf(float a, float b) {
    return __builtin_amdgcn_perm(fbits(b) + 0x8000u, fbits(a) + 0x8000u, 0x07060302u);
}
__device__ __forceinline__ u16 f2bf1(float f) { return (u16)((fbits(f) + 0x8000u) >> 16); }
__device__ __forceinline__ float bf2f(u16 u) { return bits2f(((u32)u) << 16); }
// fast softplus: v_exp + v_log instead of log1pf libcall
__device__ __forceinline__ float softplusf(float x) {
    return fmaxf(x, 0.f) + __logf(1.f + __expf(-fabsf(x)));
}
// fast sigmoid: v_rcp instead of IEEE div sequence
__device__ __forceinline__ float sigmoidf(float x) {
    return __builtin_amdgcn_rcpf(1.f + __expf(-x));
}

// Swizzle W (320x256 row-major fp32) -> wsW[kk][n][32] fragment-major bf16 (RNE, one-time)
__global__ void swizzleW(const float* __restrict__ W, u16* __restrict__ wsW) {
    int g = blockIdx.x * 256 + threadIdx.x;
    if (g >= KDIM * CDIM) return;
    int k = g >> 8, n = g & 255;
    u32 u = fbits(W[g]);
    u32 r = u + 0x7fffu + ((u >> 16) & 1u);
    wsW[((k >> 5) * 256 + n) * 32 + (k & 31)] = (u16)(r >> 16);
}

// sum(mask) -> ws[WS_CNT]
__global__ __launch_bounds__(256) void mask_cnt(const float* __restrict__ mask, float* __restrict__ ws) {
    int t = blockIdx.x * 256 + threadIdx.x;
    float s = 0.f;
    if (t < 37500) {
        const float* p = mask + (size_t)t * 16;
        #pragma unroll
        for (int i = 0; i < 4; i++) {
            float4 v = *(const float4*)(p + i * 4);
            s += (v.x + v.y) + (v.z + v.w);
        }
    }
    #pragma unroll
    for (int d = 1; d < 64; d <<= 1) s += __shfl_xor(s, d, 64);
    __shared__ float r[4];
    int l = threadIdx.x & 63, w = threadIdx.x >> 6;
    if (l == 0) r[w] = s;
    __syncthreads();
    if (threadIdx.x == 0) atomicAdd(&ws[WS_CNT], r[0] + r[1] + r[2] + r[3]);
}

// Column ownership (NEW): wave w, frag cf -> col = w*32 + cf*16 + (cf>=2 ? 96 : 0) + l15.
// cf in {0,1} covers the filter half (cols 0..127), cf in {2,3} the core half (cols 128..255)
// at the SAME l15 -> each thread holds (G[row][c], G[row][c+128]) pairs in registers.
//
// MODE 0: stats only (path-B pass 1)
// MODE 1: stats + store masked rows of H = pkbf(G[r][c], G[r][c+128]) (path-A pass 1)
// MODE 2: recompute + BN + gate + consume (path-B pass 2)
template <int MODE>
__global__ __launch_bounds__(256, 3) void gemm_pass(
    const float* __restrict__ atom, const float* __restrict__ nbrf,
    const int* __restrict__ nbridx, const float* __restrict__ mask,
    const u16* __restrict__ wsW, float* __restrict__ ws)
{
    __shared__ __align__(16) char smem[RPB * A_PITCH];   // A-tile; MODE2 reuses as g16
    __shared__ float m_lds[RPB];
    __shared__ int   idx_lds[RPB];
    __shared__ float red[(MODE == 2) ? 4 : 1][128];

    const int tid = threadIdx.x;
    const int w = tid >> 6, l = tid & 63, l15 = l & 15, l4 = l >> 4;
    const int h32 = l >> 5, c32 = l & 31;
    const int blk = blockIdx.x;
    const int r0 = blk * RPB;
    float* __restrict__ P = ws + WS_P_FOFF;

    if (tid < RPB) {
        m_lds[tid] = mask[r0 + tid];
        idx_lds[tid] = nbridx[r0 + tid];
    }
    __syncthreads();

    // ================= staging: wave w owns rows [12w, 12w+12) = atom blk*4+w =================
    // --- self features (wave-uniform atom): 32 float4 chunks, each half-wave writes 6 rows ---
    {
        float4 sv = *(const float4*)(atom + (size_t)(blk * 4 + w) * 128 + c32 * 4);
        uint2 p; p.x = pkbf(sv.x, sv.y); p.y = pkbf(sv.z, sv.w);
        #pragma unroll
        for (int jj = 0; jj < 6; ++jj) {
            int row = 12 * w + 6 * h32 + jj;
            *(uint2*)(smem + row * A_PITCH + c32 * 8) = p;
        }
    }
    // --- neighbor gather: 12 rows x 32 chunks; SKIP masked rows (dead everywhere) ---
    {
        float4 v[6]; float mrow[6];
        #pragma unroll
        for (int i = 0; i < 6; ++i) {
            int row = 12 * w + 2 * i + h32;
            mrow[i] = m_lds[row];
            if (mrow[i] != 0.f)
                v[i] = *(const float4*)(atom + (size_t)idx_lds[row] * 128 + c32 * 4);
        }
        #pragma unroll
        for (int i = 0; i < 6; ++i) {
            int row = 12 * w + 2 * i + h32;
            uint2 p; p.x = 0u; p.y = 0u;
            if (mrow[i] != 0.f) { p.x = pkbf(v[i].x, v[i].y); p.y = pkbf(v[i].z, v[i].w); }
            *(uint2*)(smem + row * A_PITCH + 256 + c32 * 8) = p;
        }
    }
    // --- nbr_fea: 12 rows x 16 chunks; SKIP masked rows ---
    {
        const float* nf = nbrf + (size_t)(r0 + 12 * w) * 64;
        float4 v[3]; float mrow[3]; int rowv[3], cv[3];
        #pragma unroll
        for (int i = 0; i < 3; ++i) {
            int g = i * 64 + l;
            rowv[i] = 12 * w + (g >> 4);
            cv[i] = g & 15;
            mrow[i] = m_lds[rowv[i]];
            if (mrow[i] != 0.f) v[i] = *(const float4*)(nf + g * 4);
        }
        #pragma unroll
        for (int i = 0; i < 3; ++i) {
            uint2 p; p.x = 0u; p.y = 0u;
            if (mrow[i] != 0.f) { p.x = pkbf(v[i].x, v[i].y); p.y = pkbf(v[i].z, v[i].w); }
            *(uint2*)(smem + rowv[i] * A_PITCH + 512 + cv[i] * 8) = p;
        }
    }
    __syncthreads();

    // ================= MFMA K-loop: 48x256 tile, paired-column wave mapping =================
    f32x4 acc[3][4];
    #pragma unroll
    for (int rf = 0; rf < 3; rf++)
        #pragma unroll
        for (int cf = 0; cf < 4; cf++)
            acc[rf][cf] = (f32x4){0.f, 0.f, 0.f, 0.f};

    const char* Ab = smem + l15 * A_PITCH + l4 * 16;
    const char* Bb = (const char*)wsW + ((size_t)w * 2048 + l15 * 64 + l4 * 16);
    frag bcur[4], bnext[4];
    #pragma unroll
    for (int cf = 0; cf < 4; ++cf)
        bcur[cf] = *(const frag*)(Bb + cf * 1024 + (cf >= 2 ? 6144 : 0));
    #pragma unroll
    for (int kk = 0; kk < KC; ++kk) {
        if (kk < KC - 1) {
            const char* Bn = Bb + (kk + 1) * 16384;
            #pragma unroll
            for (int cf = 0; cf < 4; ++cf)
                bnext[cf] = *(const frag*)(Bn + cf * 1024 + (cf >= 2 ? 6144 : 0));
        }
        frag a[3];
        #pragma unroll
        for (int rf = 0; rf < 3; rf++)
            a[rf] = *(const frag*)(Ab + rf * 16 * A_PITCH + kk * 64);
        #pragma unroll
        for (int rf = 0; rf < 3; rf++)
            #pragma unroll
            for (int cf = 0; cf < 4; cf++)
                acc[rf][cf] = __builtin_amdgcn_mfma_f32_16x16x32_bf16(a[rf], bcur[cf], acc[rf][cf], 0, 0, 0);
        #pragma unroll
        for (int cf = 0; cf < 4; ++cf) bcur[cf] = bnext[cf];
    }

    if constexpr (MODE == 0 || MODE == 1) {
        // masked column sums / sumsq -> per-block partials
        #pragma unroll
        for (int cf = 0; cf < 4; cf++) {
            float s = 0.f, q = 0.f;
            #pragma unroll
            for (int rf = 0; rf < 3; rf++)
                #pragma unroll
                for (int rg = 0; rg < 4; rg++) {
                    int row = rf * 16 + l4 * 4 + rg;
                    float mv = m_lds[row];
                    float v = acc[rf][cf][rg];
                    s += mv * v; q += mv * v * v;
                }
            s += __shfl_xor(s, 16, 64); s += __shfl_xor(s, 32, 64);
            q += __shfl_xor(q, 16, 64); q += __shfl_xor(q, 32, 64);
            if (l4 == 0) {
                int col = w * 32 + cf * 16 + (cf >= 2 ? 96 : 0) + l15;
                P[(size_t)blk * 512 + col]       = s;
                P[(size_t)blk * 512 + 256 + col] = q;
            }
        }
        if constexpr (MODE == 1) {
            // store H[row][c] = pkbf(filter, core) pairs, masked rows only.
            // lanes l15=0..15 consecutive u32 -> 64B segments, 4 rows per instr.
            u32* H = (u32*)(ws + WS_G_FOFF) + (size_t)r0 * 128 + (w * 32 + l15);
            #pragma unroll
            for (int rf = 0; rf < 3; rf++)
                #pragma unroll
                for (int rg = 0; rg < 4; rg++) {
                    const int row = rf * 16 + l4 * 4 + rg;
                    if (m_lds[row] != 0.f) {
                        H[(size_t)row * 128]      = pkbf(acc[rf][0][rg], acc[rf][2][rg]);
                        H[(size_t)row * 128 + 16] = pkbf(acc[rf][1][rg], acc[rf][3][rg]);
                    }
                }
        }
    } else {
        // ---- MODE 2: apply BN1, write normalized bf16 tile to LDS ----
        __syncthreads();   // all A-tile reads done before overwrite
        u16* g16 = (u16*)smem;
        #pragma unroll
        for (int cf = 0; cf < 4; cf++) {
            int col = w * 32 + cf * 16 + (cf >= 2 ? 96 : 0) + l15;
            float sc = ws[WS_SCALE1 + col];
            float sh = ws[WS_SHIFT1 + col];
            #pragma unroll
            for (int rf = 0; rf < 3; rf++)
                #pragma unroll
                for (int rg = 0; rg < 4; rg++) {
                    int row = rf * 16 + l4 * 4 + rg;
                    g16[row * 256 + col] = f2bf1(acc[rf][cf][rg] * sc + sh);
                }
        }
        __syncthreads();
        // ---- gated activation + reduce over M=12 -> nbr_sumed ----
        int h = tid >> 7;
        int c = tid & 127;
        float ns0 = 0.f, ns1 = 0.f;
        #pragma unroll
        for (int la2 = 0; la2 < 2; la2++) {
            int la = h * 2 + la2;
            float a_ns = 0.f;
            #pragma unroll
            for (int j = 0; j < 12; j++) {
                int row = la * 12 + j;
                float f = bf2f(g16[row * 256 + c]);
                float k = bf2f(g16[row * 256 + 128 + c]);
                a_ns += m_lds[row] * sigmoidf(f) * softplusf(k);
            }
            ws[WS_NBR + (blk * 4 + la) * 128 + c] = a_ns;
            if (la2 == 0) ns0 = a_ns; else ns1 = a_ns;
        }
        red[h][c]     = ns0 + ns1;
        red[2 + h][c] = ns0 * ns0 + ns1 * ns1;
        __syncthreads();
        if (tid < 128) {
            P[(size_t)blk * 256 + tid]       = red[0][tid] + red[1][tid];
            P[(size_t)blk * 256 + 128 + tid] = red[2][tid] + red[3][tid];
        }
    }
}

// path-A pass 2: load paired H, BN1 in f32 + gate + reduce. No LDS transpose, no MFMA.
// Thread (h, c): atoms la = h*2+{0,1}, column pair (c, c+128) via one u32 per row.
// Masked rows were never written -> skip load AND compute (wave-uniform branch).
__global__ __launch_bounds__(256) void pass2_gate(
    const float* __restrict__ ws_ro, const float* __restrict__ mask, float* __restrict__ ws)
{
    __shared__ float m_lds[RPB];
    __shared__ float red[4][128];

    const int tid = threadIdx.x;
    const int blk = blockIdx.x;
    const int h = tid >> 7, c = tid & 127;
    float* __restrict__ P = ws + WS_P_FOFF;

    if (tid < RPB) m_lds[tid] = mask[blk * RPB + tid];
    __syncthreads();

    const float scf = ws_ro[WS_SCALE1 + c],       shf = ws_ro[WS_SHIFT1 + c];
    const float sck = ws_ro[WS_SCALE1 + 128 + c], shk = ws_ro[WS_SHIFT1 + 128 + c];

    const u32* Hb = (const u32*)(ws_ro + WS_G_FOFF) + (size_t)blk * (RPB * 128) + c;

    float ns0 = 0.f, ns1 = 0.f;
    #pragma unroll
    for (int la2 = 0; la2 < 2; la2++) {
        const int la = h * 2 + la2;
        u32 v[12]; float mv[12];
        #pragma unroll
        for (int j = 0; j < 12; j++) {
            mv[j] = m_lds[la * 12 + j];
            if (mv[j] != 0.f) v[j] = Hb[(size_t)(la * 12 + j) * 128];
        }
        float a_ns = 0.f;
        #pragma unroll
        for (int j = 0; j < 12; j++) {
            if (mv[j] != 0.f) {
                const u32 u = v[j];
                float f = bits2f(u << 16)         * scf + shf;
                float k = bits2f(u & 0xffff0000u) * sck + shk;
                float sg = __builtin_amdgcn_rcpf(1.f + __expf(-f));
                float sp = fmaxf(k, 0.f) + __logf(1.f + __expf(-fabsf(k)));
                a_ns += sg * sp;        // mask is exactly 1 here
            }
        }
        ws[WS_NBR + (blk * 4 + la) * 128 + c] = a_ns;
        if (la2 == 0) ns0 = a_ns; else ns1 = a_ns;
    }
    red[h][c]     = ns0 + ns1;
    red[2 + h][c] = ns0 * ns0 + ns1 * ns1;
    __syncthreads();
    if (tid < 128) {
        P[(size_t)blk * 256 + tid]       = red[0][tid] + red[1][tid];
        P[(size_t)blk * 256 + 128 + tid] = red[2][tid] + red[3][tid];
    }
}

// reduce P1[12500][512] over blocks -> ws[WS_SUM1..] ; grid 250
__global__ __launch_bounds__(256) void red1(const float* __restrict__ ws_ro, float* __restrict__ ws) {
    const float* P = ws_ro + WS_P_FOFF;
    int c = (blockIdx.x & 1) * 256 + threadIdx.x;
    int s = blockIdx.x >> 1;
    const float* p = P + (size_t)s * 100 * 512 + c;
    float a = 0.f;
    #pragma unroll 4
    for (int r = 0; r < 100; r++) a += p[(size_t)r * 512];
    atomicAdd(&ws[WS_SUM1 + c], a);
}

// reduce P2[12500][256] over blocks -> ws[WS_SUM2..] ; grid 125
__global__ __launch_bounds__(256) void red2(const float* __restrict__ ws_ro, float* __restrict__ ws) {
    const float* P = ws_ro + WS_P_FOFF;
    int s = blockIdx.x;
    const float* p = P + (size_t)s * 100 * 256 + threadIdx.x;
    float a = 0.f;
    #pragma unroll 4
    for (int r = 0; r < 100; r++) a += p[(size_t)r * 256];
    atomicAdd(&ws[WS_SUM2 + threadIdx.x], a);
}

__global__ void finalize1(float* __restrict__ ws, const float* __restrict__ g1, const float* __restrict__ b1) {
    int c = threadIdx.x;  // 256
    float cnt = ws[WS_CNT];
    float mean = ws[WS_SUM1 + c] / cnt;
    float var  = ws[WS_SUMSQ1 + c] / cnt - mean * mean;
    float sc = g1[c] * rsqrtf(var + EPSV);
    ws[WS_SCALE1 + c] = sc;
    ws[WS_SHIFT1 + c] = b1[c] - mean * sc;
}

__global__ void finalize2(float* __restrict__ ws, const float* __restrict__ g2, const float* __restrict__ b2) {
    int c = threadIdx.x;  // 128
    float inv = 1.f / (float)N_ATOM;
    float mean = ws[WS_SUM2 + c] * inv;
    float var  = ws[WS_SUMSQ2 + c] * inv - mean * mean;
    float sc = g2[c] * rsqrtf(var + EPSV);
    ws[WS_SCALE2 + c] = sc;
    ws[WS_SHIFT2 + c] = b2[c] - mean * sc;
}

__global__ __launch_bounds__(256) void out_kernel(
    const float* __restrict__ atom, const float* __restrict__ ws, float* __restrict__ out)
{
    int g = blockIdx.x * 256 + threadIdx.x;
    if (g >= N_ATOM * 32) return;
    int i = g >> 5, c4 = (g & 31) * 4;
    float4 av = *(const float4*)(atom + i * 128 + c4);
    float4 nv = *(const float4*)(ws + WS_NBR + i * 128 + c4);
    float4 sc = *(const float4*)(ws + WS_SCALE2 + c4);
    float4 sh = *(const float4*)(ws + WS_SHIFT2 + c4);
    float4 ov;
    ov.x = softplusf(av.x + nv.x * sc.x + sh.x);
    ov.y = softplusf(av.y + nv.y * sc.y + sh.y);
    ov.z = softplusf(av.z + nv.z * sc.z + sh.z);
    ov.w = softplusf(av.w + nv.w * sc.w + sh.w);
    *(float4*)(out + i * 128 + c4) = ov;
}

extern "C" void kernel_launch(void* const* d_in, const int* in_sizes, int n_in,
                              void* d_out, int out_size, void* d_ws, size_t ws_size,
                              hipStream_t stream) {
    (void)in_sizes; (void)n_in; (void)out_size;
    const float* atom = (const float*)d_in[0];
    const float* nbrf = (const float*)d_in[1];
    const int*   nidx = (const int*)d_in[2];
    const float* mask = (const float*)d_in[3];
    const float* W    = (const float*)d_in[4];
    // d_in[5] = b_fc: zeros AND cancels exactly through BN1 for masked rows; unused
    const float* g1 = (const float*)d_in[6];
    const float* b1 = (const float*)d_in[7];
    const float* g2 = (const float*)d_in[8];
    const float* b2 = (const float*)d_in[9];
    float* ws  = (float*)d_ws;
    u16*  wsW  = (u16*)((char*)d_ws + (size_t)WS_W_FOFF * 4);
    float* out = (float*)d_out;
    const bool bigws = (ws_size >= WS_NEED_BYTES);

    hipMemsetAsync(d_ws, 0, WS_STATS_END * 4, stream);
    swizzleW<<<(KDIM * CDIM + 255) / 256, 256, 0, stream>>>(W, wsW);
    mask_cnt<<<147, 256, 0, stream>>>(mask, ws);
    if (bigws) {
        gemm_pass<1><<<NBLK, 256, 0, stream>>>(atom, nbrf, nidx, mask, wsW, ws);
        red1<<<250, 256, 0, stream>>>(ws, ws);
        finalize1<<<1, 256, 0, stream>>>(ws, g1, b1);
        pass2_gate<<<NBLK, 256, 0, stream>>>(ws, mask, ws);
    } else {
        gemm_pass<0><<<NBLK, 256, 0, stream>>>(atom, nbrf, nidx, mask, wsW, ws);
        red1<<<250, 256, 0, stream>>>(ws, ws);
        finalize1<<<1, 256, 0, stream>>>(ws, g1, b1);
        gemm_pass<2><<<NBLK, 256, 0, stream>>>(atom, nbrf, nidx, mask, wsW, ws);
    }
    red2<<<125, 256, 0, stream>>>(ws, ws);
    finalize2<<<1, 128, 0, stream>>>(ws, g2, b2);
    out_kernel<<<(N_ATOM * 32 + 255) / 256, 256, 0, stream>>>(atom, ws, out);
}